// Round 1
// baseline (154.451 us; speedup 1.0000x reference)
//
#include <hip/hip_runtime.h>
#include <hip/hip_bf16.h>

// TVConv: per-pixel spatially-varying 3x3 depthwise conv.
// x:           (B=8, C=96, H=128, W=128)  fp32
// weight_maps: (1,  C=96, 3, 3, H, W)     fp32
// out:         (B, C, H, W)               fp32
//
// out[b,c,h,w] = sum_{i,j in 0..2} wm[c,i,j,h,w] * xpad[b,c,h+i-1, w+j-1]
//
// Memory-bound: 157 MB compulsory traffic -> ~25 us floor @6.3 TB/s.
// Strategy: one thread per (c,h,w4) where w4 is a 4-pixel float4 segment;
// loop over b INSIDE the thread so the 9 weight float4s (batch-invariant,
// largest input) are loaded exactly once per thread. All global accesses
// are float4 except the two halo scalars per row, which hit cache lines
// fetched by neighbor threads.

namespace {
constexpr int B = 8, C = 96, H = 128, W = 128;
constexpr int HW = H * W;
constexpr int W4 = W / 4;  // 32 segments per row
}

__global__ __launch_bounds__(256) void tvconv_kernel(
    const float* __restrict__ x,
    const float* __restrict__ wm,
    float* __restrict__ out) {
  const int tid = blockIdx.x * blockDim.x + threadIdx.x;  // over C*H*W4
  const int w4 = tid & (W4 - 1);         // 5 bits
  const int h  = (tid >> 5) & (H - 1);   // 7 bits
  const int c  = tid >> 12;              // channel
  if (c >= C) return;
  const int w = w4 * 4;

  // Load the 9 per-pixel weights for this (c,h,w..w+3): 9 float4 loads.
  float wt[3][3][4];
  const float* wp = wm + (size_t)c * 9 * HW + h * W + w;
  #pragma unroll
  for (int i = 0; i < 3; ++i) {
    #pragma unroll
    for (int j = 0; j < 3; ++j) {
      const float4 v = *reinterpret_cast<const float4*>(wp + (size_t)(i * 3 + j) * HW);
      wt[i][j][0] = v.x; wt[i][j][1] = v.y; wt[i][j][2] = v.z; wt[i][j][3] = v.w;
    }
  }

  #pragma unroll
  for (int b = 0; b < B; ++b) {
    const float* xb = x + ((size_t)b * C + c) * HW;
    float acc[4] = {0.f, 0.f, 0.f, 0.f};
    #pragma unroll
    for (int i = 0; i < 3; ++i) {
      const int hh = h + i - 1;
      if (hh < 0 || hh >= H) continue;  // zero pad row -> contributes 0
      const float* xr = xb + hh * W + w;
      const float4 ctr = *reinterpret_cast<const float4*>(xr);
      const float left  = (w > 0)     ? xr[-1] : 0.f;  // zero pad col
      const float right = (w + 4 < W) ? xr[4]  : 0.f;
      // xv[m] = x[hh][w-1+m], m in 0..5
      const float xv[6] = {left, ctr.x, ctr.y, ctr.z, ctr.w, right};
      #pragma unroll
      for (int j = 0; j < 3; ++j) {
        #pragma unroll
        for (int k = 0; k < 4; ++k) {
          acc[k] += wt[i][j][k] * xv[k + j];  // tap j of pixel w+k reads x[w+k+j-1]
        }
      }
    }
    float4 o;
    o.x = acc[0]; o.y = acc[1]; o.z = acc[2]; o.w = acc[3];
    *reinterpret_cast<float4*>(out + ((size_t)b * C + c) * HW + h * W + w) = o;
  }
}

extern "C" void kernel_launch(void* const* d_in, const int* in_sizes, int n_in,
                              void* d_out, int out_size, void* d_ws, size_t ws_size,
                              hipStream_t stream) {
  const float* x  = (const float*)d_in[0];
  const float* wm = (const float*)d_in[1];
  float* out = (float*)d_out;

  const int total_threads = C * H * W4;          // 393216
  const int block = 256;
  const int grid = (total_threads + block - 1) / block;  // 1536
  tvconv_kernel<<<grid, block, 0, stream>>>(x, wm, out);
}

// Round 2
// 142.890 us; speedup vs baseline: 1.0809x; 1.0809x over previous
//
#include <hip/hip_runtime.h>
#include <hip/hip_bf16.h>

// TVConv: per-pixel spatially-varying 3x3 depthwise conv.
// x:           (B=8, C=96, H=128, W=128)  fp32
// weight_maps: (1,  C=96, 3, 3, H, W)     fp32
// out:         (B, C, H, W)               fp32
//
// R1 analysis: 60us @ 1.8 TB/s, VGPR=36 -> MLP-bound (too few loads in
// flight). This version: batch split 2-way over gridDim.y (4 b/thread),
// ALL 21 float4 loads (9 wt + 12 x) prefetched into registers before
// compute, halo pixels via __shfl (lane boundary == W-padding boundary,
// so masking is exact). Target ~120 VGPR, 4 waves/SIMD, ~84 loads in
// flight per SIMD.

namespace {
constexpr int B = 8, C = 96, H = 128, W = 128;
constexpr int HW = H * W;
constexpr int W4 = W / 4;  // 32 float4 segments per row
}

__global__ __launch_bounds__(256, 4) void tvconv_kernel(
    const float* __restrict__ x,
    const float* __restrict__ wm,
    float* __restrict__ out) {
  const int tid = blockIdx.x * 256 + threadIdx.x;  // over C*H*W4
  const int w4 = tid & (W4 - 1);         // 5 bits
  const int h  = (tid >> 5) & (H - 1);   // 7 bits
  const int c  = tid >> 12;              // channel
  const int w  = w4 * 4;
  const int b0 = blockIdx.y * 4;         // batch half: 0..3 or 4..7

  // ---- Prefetch phase: issue all 21 float4 loads back-to-back ----
  // 9 per-pixel weights for (c, h, w..w+3)
  float4 wt[9];
  const float* wp = wm + (size_t)c * 9 * HW + h * W + w;
#pragma unroll
  for (int k = 0; k < 9; ++k) {
    wt[k] = *reinterpret_cast<const float4*>(wp + (size_t)k * HW);
  }

  // x rows h-1, h, h+1 for 4 batches (zero4 for padded rows: tap * 0 == 0)
  const bool hlo = (h > 0), hhi = (h < H - 1);
  const float4 zero4 = make_float4(0.f, 0.f, 0.f, 0.f);
  float4 xr[4][3];
#pragma unroll
  for (int bb = 0; bb < 4; ++bb) {
    const float* xb = x + ((size_t)(b0 + bb) * C + c) * HW + h * W + w;
    float4 up = zero4, dn = zero4;
    if (hlo) up = *reinterpret_cast<const float4*>(xb - W);
    const float4 mid = *reinterpret_cast<const float4*>(xb);
    if (hhi) dn = *reinterpret_cast<const float4*>(xb + W);
    xr[bb][0] = up; xr[bb][1] = mid; xr[bb][2] = dn;
  }

  // ---- Compute phase ----
  const bool at_left  = (w4 == 0);        // lanes 0 and 32: w == 0
  const bool at_right = (w4 == W4 - 1);   // lanes 31 and 63: w+4 == W
#pragma unroll
  for (int bb = 0; bb < 4; ++bb) {
    float acc[4] = {0.f, 0.f, 0.f, 0.f};
#pragma unroll
    for (int i = 0; i < 3; ++i) {
      const float4 ctr = xr[bb][i];
      // halo from neighbor lanes; wave rows: lanes 0-31 = row h, 32-63 = h+1,
      // and the cross-row pulls at lanes 0/32/31/63 are exactly the padded
      // columns -> masked to 0.
      float left  = __shfl_up(ctr.w, 1);
      float right = __shfl_down(ctr.x, 1);
      if (at_left)  left  = 0.f;
      if (at_right) right = 0.f;
      // xv[m] = x[h+i-1][w-1+m], m in 0..5
      const float xv[6] = {left, ctr.x, ctr.y, ctr.z, ctr.w, right};
#pragma unroll
      for (int j = 0; j < 3; ++j) {
        const float4 wv = wt[i * 3 + j];
        const float wa[4] = {wv.x, wv.y, wv.z, wv.w};
#pragma unroll
        for (int k = 0; k < 4; ++k) {
          acc[k] += wa[k] * xv[k + j];  // pixel w+k, tap j reads x[w+k+j-1]
        }
      }
    }
    float4 o;
    o.x = acc[0]; o.y = acc[1]; o.z = acc[2]; o.w = acc[3];
    *reinterpret_cast<float4*>(
        out + ((size_t)(b0 + bb) * C + c) * HW + h * W + w) = o;
  }
}

extern "C" void kernel_launch(void* const* d_in, const int* in_sizes, int n_in,
                              void* d_out, int out_size, void* d_ws, size_t ws_size,
                              hipStream_t stream) {
  const float* x  = (const float*)d_in[0];
  const float* wm = (const float*)d_in[1];
  float* out = (float*)d_out;

  const int total_threads = C * H * W4;  // 393216 per batch-half
  const int block = 256;
  dim3 grid((total_threads + block - 1) / block, B / 4);  // (1536, 2)
  tvconv_kernel<<<grid, dim3(block, 1, 1), 0, stream>>>(x, wm, out);
}

// Round 4
// 142.258 us; speedup vs baseline: 1.0857x; 1.0044x over previous
//
#include <hip/hip_runtime.h>
#include <hip/hip_bf16.h>

// TVConv: per-pixel spatially-varying 3x3 depthwise conv.
// x:           (B=8, C=96, H=128, W=128)  fp32
// weight_maps: (1,  C=96, 3, 3, H, W)     fp32
// out:         (B, C, H, W)               fp32
//
// R2: 46us @ 3.0 TB/s — register-destination loads cap in-flight bytes at
// the VGPR file (~8 KB/CU); need ~10-15 KB/CU for streaming BW. Fix: stage
// the 9 weight float4s per thread via async global_load_lds (LDS-dest
// loads consume no VGPRs). R3 aborted; R4 uses the m97-canonical form:
// per-lane LDS pointer base+tid*16 (HW readfirstlanes it; lane0's value is
// the wave base, layout = uniform base + lane*16 as required), plus 1 KB
// LDS slack so no write ends exactly at the allocation boundary.

namespace {
constexpr int B = 8, C = 96, H = 128, W = 128;
constexpr int HW = H * W;
constexpr int W4 = W / 4;  // 32 float4 segments per row
}

typedef __attribute__((address_space(1))) void gbl_void;
typedef __attribute__((address_space(3))) void lds_void;

__global__ __launch_bounds__(256, 4) void tvconv_kernel(
    const float* __restrict__ x,
    const float* __restrict__ wm,
    float* __restrict__ out) {
  // 9 taps x 256 threads x 16 B = 36864 B, +1024 slack -> 4 blocks/CU.
  __shared__ __align__(16) char smem_c[9 * 4096 + 1024];

  const int t   = threadIdx.x;
  const int tid = blockIdx.x * 256 + t;      // over C*H*W4
  const int w4  = tid & (W4 - 1);            // 5 bits
  const int h   = (tid >> 5) & (H - 1);      // 7 bits
  const int c   = tid >> 12;                 // channel
  const int w   = w4 * 4;
  const int b0  = blockIdx.y * 4;            // batch half: 0..3 or 4..7

  // ---- Async-stage the 9 per-pixel weight float4s into LDS ----
  // LDS byte addr for (tap k, thread t) = k*4096 + t*16. Pass the per-lane
  // pointer; HW uses wave-uniform base (lane0's value) + lane*16, which
  // lands every lane at exactly k*4096 + t*16.
  const float* wp = wm + (size_t)c * 9 * HW + h * W + w;
#pragma unroll
  for (int k = 0; k < 9; ++k) {
    __builtin_amdgcn_global_load_lds(
        (const gbl_void*)(wp + (size_t)k * HW),
        (lds_void*)(smem_c + k * 4096 + t * 16),
        16, 0, 0);
  }

  // ---- x rows h-1, h, h+1 for 4 batches: register float4 loads ----
  const bool hlo = (h > 0), hhi = (h < H - 1);
  const float4 zero4 = make_float4(0.f, 0.f, 0.f, 0.f);
  float4 xr[4][3];
#pragma unroll
  for (int bb = 0; bb < 4; ++bb) {
    const float* xb = x + ((size_t)(b0 + bb) * C + c) * HW + h * W + w;
    float4 up = zero4, dn = zero4;
    if (hlo) up = *reinterpret_cast<const float4*>(xb - W);
    const float4 mid = *reinterpret_cast<const float4*>(xb);
    if (hhi) dn = *reinterpret_cast<const float4*>(xb + W);
    xr[bb][0] = up; xr[bb][1] = mid; xr[bb][2] = dn;
  }

  // Wait for async LDS writes (compiler drains vmcnt before s_barrier).
  __syncthreads();

  // ---- Compute ----
  const bool at_left  = (w4 == 0);
  const bool at_right = (w4 == W4 - 1);
  float acc[4][4];
#pragma unroll
  for (int bb = 0; bb < 4; ++bb)
#pragma unroll
    for (int m = 0; m < 4; ++m) acc[bb][m] = 0.f;

#pragma unroll
  for (int i = 0; i < 3; ++i) {
    // xv[bb][m] = x[h+i-1][w-1+m], m in 0..5; halo via shfl. Cross-row
    // pulls at lanes 0/32/31/63 are exactly the padded columns -> masked.
    float xv[4][6];
#pragma unroll
    for (int bb = 0; bb < 4; ++bb) {
      const float4 ctr = xr[bb][i];
      float left  = __shfl_up(ctr.w, 1);
      float right = __shfl_down(ctr.x, 1);
      if (at_left)  left  = 0.f;
      if (at_right) right = 0.f;
      xv[bb][0] = left;  xv[bb][1] = ctr.x; xv[bb][2] = ctr.y;
      xv[bb][3] = ctr.z; xv[bb][4] = ctr.w; xv[bb][5] = right;
    }
#pragma unroll
    for (int j = 0; j < 3; ++j) {
      const float4 wv = *reinterpret_cast<const float4*>(
          smem_c + (i * 3 + j) * 4096 + t * 16);  // ds_read_b128
      const float wa[4] = {wv.x, wv.y, wv.z, wv.w};
#pragma unroll
      for (int bb = 0; bb < 4; ++bb)
#pragma unroll
        for (int m = 0; m < 4; ++m)
          acc[bb][m] += wa[m] * xv[bb][m + j];
    }
  }

#pragma unroll
  for (int bb = 0; bb < 4; ++bb) {
    float4 o;
    o.x = acc[bb][0]; o.y = acc[bb][1]; o.z = acc[bb][2]; o.w = acc[bb][3];
    *reinterpret_cast<float4*>(
        out + ((size_t)(b0 + bb) * C + c) * HW + h * W + w) = o;
  }
}

extern "C" void kernel_launch(void* const* d_in, const int* in_sizes, int n_in,
                              void* d_out, int out_size, void* d_ws, size_t ws_size,
                              hipStream_t stream) {
  const float* x  = (const float*)d_in[0];
  const float* wm = (const float*)d_in[1];
  float* out = (float*)d_out;

  const int total_threads = C * H * W4;  // 393216 per batch-half
  const int block = 256;
  dim3 grid((total_threads + block - 1) / block, B / 4);  // (1536, 2)
  tvconv_kernel<<<grid, dim3(block, 1, 1), 0, stream>>>(x, wm, out);
}